// Round 1
// baseline (530.089 us; speedup 1.0000x reference)
//
#include <hip/hip_runtime.h>
#include <hip/hip_bf16.h>

#define DEV __device__ __forceinline__

typedef __attribute__((ext_vector_type(8))) short bf16x8;
typedef __attribute__((ext_vector_type(4))) float f32x4;
typedef __attribute__((ext_vector_type(4))) unsigned short u16x4;
typedef __attribute__((ext_vector_type(8))) unsigned short u16x8;

// ---- constants: B=2, L=2048, D=512, H=8, HD=64, NL=4 ----

DEV unsigned short f2bf(float f) {
  union { float f; unsigned u; } v; v.f = f;
  unsigned r = v.u + 0x7FFFu + ((v.u >> 16) & 1u);
  return (unsigned short)(r >> 16);
}

DEV void gload_lds16(const void* g, void* lds) {
  __builtin_amdgcn_global_load_lds(
      (const __attribute__((address_space(1))) unsigned int*)g,
      (__attribute__((address_space(3))) unsigned int*)lds, 16, 0, 0);
}

// byte offset into a [rows][64 bf16] (128B-row) tile with XOR swizzle
DEV int swz128(int r, int cb) { return r * 128 + (cb ^ ((r & 7) << 4)); }

// ---------------- fp32 -> bf16 weight convert ----------------
__global__ __launch_bounds__(256) void cvt_kernel(const float* __restrict__ s,
                                                  unsigned short* __restrict__ d, int n4) {
  int i = blockIdx.x * 256 + threadIdx.x;
  if (i >= n4) return;
  float4 v = ((const float4*)s)[i];
  u16x4 r; r[0] = f2bf(v.x); r[1] = f2bf(v.y); r[2] = f2bf(v.z); r[3] = f2bf(v.w);
  ((u16x4*)d)[i] = r;
}

// ---------------- x = base + timing_signal ----------------
__global__ __launch_bounds__(256) void init_x_kernel(const float* __restrict__ base,
                                                     float* __restrict__ xf,
                                                     unsigned short* __restrict__ xb) {
  int i = blockIdx.x * 256 + threadIdx.x;          // 0 .. 2*2048*512-1
  int d = i & 511;
  int l = (i >> 9) & 2047;
  const float NEG_INC = -(float)(9.210340371976184 / 255.0);  // -ln(10000)/255
  int j = d & 255;
  float w = expf((float)j * NEG_INC);
  float ang = (float)(l - 1) * w;
  float ts = (d < 256) ? sinf(ang) : cosf(ang);
  float v = base[i] + ts;
  xf[i] = v;
  xb[i] = f2bf(v);
}

// ---------------- GEMM: C[M,N] = A[M,512] @ W[N,512]^T (+bias, +epilogue) ----------------
// MODE 0: out bf16 = acc + bias   (QKV; q-columns (<512) pre-scaled by 1/8)
// MODE 1: out f32 = acc + bias + resid; writes block partial sum/sumsq
// MODE 2: out f32 = relu(acc + bias) + resid; writes block partial sum/sumsq
template<int MODE, int BN>
__global__ __launch_bounds__(256) void gemm_kernel(
    const unsigned short* __restrict__ A,
    const unsigned short* __restrict__ W,
    const float* __restrict__ bias,
    const float* __restrict__ resid,
    unsigned short* __restrict__ outb,
    float* __restrict__ outf,
    float* __restrict__ partials,
    int N) {
  constexpr int FN = BN / 32;
  __shared__ __align__(16) unsigned short Al[128 * 64];
  __shared__ __align__(16) unsigned short Bl[BN * 64];
  __shared__ float red[8];
  const int tid = threadIdx.x;
  const int lane = tid & 63, wid = tid >> 6;
  const int wr = wid >> 1, wc = wid & 1;
  const int m0 = blockIdx.y * 128, n0 = blockIdx.x * BN;

  f32x4 acc[4][FN];
#pragma unroll
  for (int m = 0; m < 4; ++m)
#pragma unroll
    for (int n = 0; n < FN; ++n) acc[m][n] = (f32x4){0.f, 0.f, 0.f, 0.f};

  for (int kt = 0; kt < 8; ++kt) {
    __syncthreads();
    // stage A tile [128][64] (rows of A, K-slice kt*64)
#pragma unroll
    for (int it = 0; it < 4; ++it) {
      int c = it * 256 + tid;
      int row = c >> 3, sub = c & 7;
      gload_lds16((const char*)A + (m0 + row) * 1024 + kt * 128 + sub * 16,
                  (char*)Al + (it * 256 + wid * 64) * 16);
    }
    // stage B tile [BN][64] (rows of W)
#pragma unroll
    for (int it = 0; it < BN / 32; ++it) {
      int c = it * 256 + tid;
      int row = c >> 3, sub = c & 7;
      gload_lds16((const char*)W + (n0 + row) * 1024 + kt * 128 + sub * 16,
                  (char*)Bl + (it * 256 + wid * 64) * 16);
    }
    __syncthreads();
#pragma unroll
    for (int ks = 0; ks < 2; ++ks) {
      bf16x8 af[4], bfr[FN];
#pragma unroll
      for (int m = 0; m < 4; ++m)
        af[m] = *(const bf16x8*)&Al[(wr * 64 + m * 16 + (lane & 15)) * 64 + ks * 32 + (lane >> 4) * 8];
#pragma unroll
      for (int n = 0; n < FN; ++n)
        bfr[n] = *(const bf16x8*)&Bl[(wc * (BN / 2) + n * 16 + (lane & 15)) * 64 + ks * 32 + (lane >> 4) * 8];
#pragma unroll
      for (int m = 0; m < 4; ++m)
#pragma unroll
        for (int n = 0; n < FN; ++n)
          acc[m][n] = __builtin_amdgcn_mfma_f32_16x16x32_bf16(af[m], bfr[n], acc[m][n], 0, 0, 0);
    }
  }

  float ps = 0.f, ps2 = 0.f;
#pragma unroll
  for (int m = 0; m < 4; ++m) {
    int row = m0 + wr * 64 + m * 16 + ((lane >> 4) << 2);
#pragma unroll
    for (int n = 0; n < FN; ++n) {
      int col = n0 + wc * (BN / 2) + n * 16 + (lane & 15);
      float bv = bias[col];
#pragma unroll
      for (int j = 0; j < 4; ++j) {
        float v = acc[m][n][j] + bv;
        int idx = (row + j) * N + col;
        if (MODE == 0) {
          if (col < 512) v *= 0.125f;  // fold 1/sqrt(HD) into Q
          outb[idx] = f2bf(v);
        } else {
          if (MODE == 2) v = fmaxf(v, 0.f);
          v += resid[idx];
          outf[idx] = v;
          ps += v; ps2 += v * v;
        }
      }
    }
  }
  if (MODE != 0) {
#pragma unroll
    for (int s = 1; s < 64; s <<= 1) {
      ps += __shfl_xor(ps, s);
      ps2 += __shfl_xor(ps2, s);
    }
    if (lane == 0) { red[wid * 2] = ps; red[wid * 2 + 1] = ps2; }
    __syncthreads();
    if (tid == 0) {
      float s = red[0] + red[2] + red[4] + red[6];
      float s2 = red[1] + red[3] + red[5] + red[7];
      int batch = blockIdx.y >> 4;
      int slot = (blockIdx.y & 15) * (N / BN) + blockIdx.x;
      partials[(batch * 128 + slot) * 2] = s;
      partials[(batch * 128 + slot) * 2 + 1] = s2;
    }
  }
}

// ---------------- V transpose: vT[b][h][d][l] = qkv[b][l][1024 + h*64 + d] ----------------
__global__ __launch_bounds__(256) void vtrans_kernel(const unsigned short* __restrict__ qkv,
                                                     unsigned short* __restrict__ vT) {
  __shared__ unsigned short tile[64][65];
  const int tid = threadIdx.x;
  const int l0 = blockIdx.x * 64;
  const int b = blockIdx.y >> 3, h = blockIdx.y & 7;
#pragma unroll
  for (int it = 0; it < 2; ++it) {
    int c = it * 256 + tid;
    int lrow = c >> 3, d0 = (c & 7) * 8;
    u16x8 v = *(const u16x8*)&qkv[(size_t)(b * 2048 + l0 + lrow) * 1536 + 1024 + h * 64 + d0];
#pragma unroll
    for (int e = 0; e < 8; ++e) tile[lrow][d0 + e] = v[e];
  }
  __syncthreads();
#pragma unroll
  for (int it = 0; it < 2; ++it) {
    int c = it * 256 + tid;
    int drow = c >> 3, lc = (c & 7) * 8;
    u16x8 w;
#pragma unroll
    for (int e = 0; e < 8; ++e) w[e] = tile[lc + e][drow];
    *(u16x8*)&vT[((size_t)(b * 8 + h) * 64 + drow) * 2048 + l0 + lc] = w;
  }
}

// ---------------- flash attention: o[b][l][h*64+d] ----------------
__global__ __launch_bounds__(256) void attn_kernel(
    const unsigned short* __restrict__ qkv,   // [B,L,1536] bf16 (q pre-scaled 1/8)
    const unsigned short* __restrict__ vT,    // [B,H,64,L] bf16
    unsigned short* __restrict__ o) {         // [B,L,512] bf16
  __shared__ __align__(16) unsigned short Ql[64 * 64];
  __shared__ __align__(16) unsigned short Kl[64 * 64];
  __shared__ __align__(16) unsigned short Vl[64 * 64];
  __shared__ __align__(16) unsigned short Pl[64 * 64];
  const int tid = threadIdx.x;
  const int lane = tid & 63, wid = tid >> 6;
  const int l0 = blockIdx.x * 64;
  const int b = blockIdx.y >> 3, h = blockIdx.y & 7;

  const size_t qoff = (size_t)b * 2048 * 1536 + h * 64;
  const size_t koff = qoff + 512;
  const size_t voff = (size_t)(b * 8 + h) * 64 * 2048;

  // stage Q tile [64][64] once (pre-swizzled source -> swizzled linear LDS)
#pragma unroll
  for (int it = 0; it < 2; ++it) {
    int c = it * 256 + tid;
    int row = c >> 3, sub = c & 7;
    int sw = (sub * 16) ^ ((row & 7) << 4);
    gload_lds16((const char*)qkv + (qoff + (size_t)(l0 + row) * 1536) * 2 + sw,
                (char*)Ql + (it * 256 + wid * 64) * 16);
  }

  float mrow[4] = {-1e30f, -1e30f, -1e30f, -1e30f};
  float ssum[4] = {0.f, 0.f, 0.f, 0.f};
  f32x4 oacc[4];
#pragma unroll
  for (int df = 0; df < 4; ++df) oacc[df] = (f32x4){0.f, 0.f, 0.f, 0.f};

  for (int t = 0; t < 32; ++t) {
    __syncthreads();
#pragma unroll
    for (int it = 0; it < 2; ++it) {
      int c = it * 256 + tid;
      int row = c >> 3, sub = c & 7;
      int sw = (sub * 16) ^ ((row & 7) << 4);
      gload_lds16((const char*)qkv + (koff + (size_t)(t * 64 + row) * 1536) * 2 + sw,
                  (char*)Kl + (it * 256 + wid * 64) * 16);
    }
#pragma unroll
    for (int it = 0; it < 2; ++it) {
      int c = it * 256 + tid;
      int row = c >> 3, sub = c & 7;
      int sw = (sub * 16) ^ ((row & 7) << 4);
      gload_lds16((const char*)vT + (voff + (size_t)row * 2048 + t * 64) * 2 + sw,
                  (char*)Vl + (it * 256 + wid * 64) * 16);
    }
    __syncthreads();

    // S^ = (Q/8) K^T for this wave's 16 q rows; D[q][kv] layout
    bf16x8 aq[2];
#pragma unroll
    for (int ks = 0; ks < 2; ++ks) {
      int r = wid * 16 + (lane & 15);
      aq[ks] = *(const bf16x8*)((const char*)Ql + swz128(r, ks * 64 + (lane >> 4) * 16));
    }
    f32x4 sf[4];
#pragma unroll
    for (int kvf = 0; kvf < 4; ++kvf) {
      f32x4 s4 = (f32x4){0.f, 0.f, 0.f, 0.f};
#pragma unroll
      for (int ks = 0; ks < 2; ++ks) {
        int r = kvf * 16 + (lane & 15);
        bf16x8 bk = *(const bf16x8*)((const char*)Kl + swz128(r, ks * 64 + (lane >> 4) * 16));
        s4 = __builtin_amdgcn_mfma_f32_16x16x32_bf16(aq[ks], bk, s4, 0, 0, 0);
      }
      sf[kvf] = s4;
    }

    char* pw = (char*)Pl + wid * 2048;  // wave-private P region [16][64]
#pragma unroll
    for (int j = 0; j < 4; ++j) {
      float mx = fmaxf(fmaxf(sf[0][j], sf[1][j]), fmaxf(sf[2][j], sf[3][j]));
      mx = fmaxf(mx, __shfl_xor(mx, 1));
      mx = fmaxf(mx, __shfl_xor(mx, 2));
      mx = fmaxf(mx, __shfl_xor(mx, 4));
      mx = fmaxf(mx, __shfl_xor(mx, 8));
      float mn = fmaxf(mrow[j], mx);
      float corr = __expf(mrow[j] - mn);
      mrow[j] = mn;
      float rs = 0.f;
#pragma unroll
      for (int kvf = 0; kvf < 4; ++kvf) {
        float p = __expf(sf[kvf][j] - mn);
        sf[kvf][j] = p;
        rs += p;
      }
      rs += __shfl_xor(rs, 1);
      rs += __shfl_xor(rs, 2);
      rs += __shfl_xor(rs, 4);
      rs += __shfl_xor(rs, 8);
      ssum[j] = ssum[j] * corr + rs;
#pragma unroll
      for (int df = 0; df < 4; ++df) oacc[df][j] *= corr;
      int r = ((lane >> 4) << 2) + j;
#pragma unroll
      for (int kvf = 0; kvf < 4; ++kvf) {
        int cb = (kvf * 16 + (lane & 15)) * 2;
        *(unsigned short*)(pw + swz128(r, cb)) = f2bf(sf[kvf][j]);
      }
    }
    __syncthreads();

    // O += P V  (A = P rows, B = Vt rows)
#pragma unroll
    for (int ks = 0; ks < 2; ++ks) {
      int rp = lane & 15;
      bf16x8 ap = *(const bf16x8*)((const char*)pw + swz128(rp, ks * 64 + (lane >> 4) * 16));
#pragma unroll
      for (int df = 0; df < 4; ++df) {
        int rv = df * 16 + (lane & 15);
        bf16x8 bv = *(const bf16x8*)((const char*)Vl + swz128(rv, ks * 64 + (lane >> 4) * 16));
        oacc[df] = __builtin_amdgcn_mfma_f32_16x16x32_bf16(ap, bv, oacc[df], 0, 0, 0);
      }
    }
  }

  int orow = l0 + wid * 16 + ((lane >> 4) << 2);
  int ocol = h * 64 + (lane & 15);
#pragma unroll
  for (int j = 0; j < 4; ++j) {
    float inv = 1.f / ssum[j];
#pragma unroll
    for (int df = 0; df < 4; ++df)
      o[(size_t)(b * 2048 + orow + j) * 512 + ocol + df * 16] = f2bf(oacc[df][j] * inv);
  }
}

// ---------------- global norm apply: out = (in - mean)/sd * scale + bias ----------------
__global__ __launch_bounds__(256) void norm_kernel(
    const float* __restrict__ in,
    const float* __restrict__ partials,   // [2][128][2]
    const float* __restrict__ scale_arr,
    const float* __restrict__ bias_arr,
    int layer,
    float* __restrict__ outf,
    unsigned short* __restrict__ outb,
    float* __restrict__ outf2) {
  int i4 = blockIdx.x * 256 + threadIdx.x;  // 0..524287
  size_t i = (size_t)i4 * 4;
  int batch = (int)(i >> 20);
  const float* p = partials + batch * 256;
  int lane = threadIdx.x & 63;
  float s = 0.f, s2 = 0.f;
  for (int k = lane; k < 128; k += 64) { s += p[k * 2]; s2 += p[k * 2 + 1]; }
#pragma unroll
  for (int m = 1; m < 64; m <<= 1) { s += __shfl_xor(s, m); s2 += __shfl_xor(s2, m); }
  const float invn = 1.f / 1048576.f;
  float mean = s * invn;
  float var = s2 * invn - mean * mean;
  float a = scale_arr[layer] / sqrtf(var);
  float bi = bias_arr[layer] - mean * a;
  float4 v = *(const float4*)(in + i);
  float4 r;
  r.x = v.x * a + bi; r.y = v.y * a + bi; r.z = v.z * a + bi; r.w = v.w * a + bi;
  *(float4*)(outf + i) = r;
  u16x4 rb; rb[0] = f2bf(r.x); rb[1] = f2bf(r.y); rb[2] = f2bf(r.z); rb[3] = f2bf(r.w);
  *(u16x4*)(outb + i) = rb;
  if (outf2) *(float4*)(outf2 + i) = r;
}

extern "C" void kernel_launch(void* const* d_in, const int* in_sizes, int n_in,
                              void* d_out, int out_size, void* d_ws, size_t ws_size,
                              hipStream_t stream) {
  (void)in_sizes; (void)n_in; (void)out_size; (void)ws_size;
  const float* base  = (const float*)d_in[0];
  const float* qkv_w = (const float*)d_in[1];
  const float* qkv_b = (const float*)d_in[2];
  const float* f1_w  = (const float*)d_in[3];
  const float* f1_b  = (const float*)d_in[4];
  const float* f2_w  = (const float*)d_in[5];
  const float* f2_b  = (const float*)d_in[6];
  const float* n1s   = (const float*)d_in[7];
  const float* n1b   = (const float*)d_in[8];
  const float* n2s   = (const float*)d_in[9];
  const float* n2b   = (const float*)d_in[10];

  char* ws = (char*)d_ws;
  float*          x_f32  = (float*)(ws + 0);                     // 8 MB
  unsigned short* x_bf   = (unsigned short*)(ws + (8u << 20));   // 4 MB
  unsigned short* qkv_bf = (unsigned short*)(ws + (12u << 20));  // 12 MB
  unsigned short* h_bf   = qkv_bf;                               // alias (qkv dead after attn)
  unsigned short* o_bf   = (unsigned short*)(ws + (24u << 20));  // 4 MB
  float*          t_f32  = (float*)(ws + (28u << 20));           // 8 MB
  unsigned short* vT     = (unsigned short*)(ws + (28u << 20));  // alias (vT dead before f1 writes t)
  float*          h_f32  = (float*)(ws + (36u << 20));           // 8 MB
  unsigned short* wq     = (unsigned short*)(ws + (44u << 20));  // 6 MB
  unsigned short* w1     = (unsigned short*)(ws + (50u << 20));  // 2 MB
  unsigned short* w2     = (unsigned short*)(ws + (52u << 20));  // 2 MB
  float*          parts  = (float*)(ws + (54u << 20));           // 2 KB

  cvt_kernel<<<3072, 256, 0, stream>>>(qkv_w, wq, 786432);
  cvt_kernel<<<1024, 256, 0, stream>>>(f1_w, w1, 262144);
  cvt_kernel<<<1024, 256, 0, stream>>>(f2_w, w2, 262144);
  init_x_kernel<<<8192, 256, 0, stream>>>(base, x_f32, x_bf);

  for (int L = 0; L < 4; ++L) {
    gemm_kernel<0, 128><<<dim3(12, 32), 256, 0, stream>>>(
        x_bf, wq + L * 786432, qkv_b + L * 1536, nullptr, qkv_bf, nullptr, nullptr, 1536);
    vtrans_kernel<<<dim3(32, 16), 256, 0, stream>>>(qkv_bf, vT);
    attn_kernel<<<dim3(32, 16), 256, 0, stream>>>(qkv_bf, vT, o_bf);
    gemm_kernel<1, 64><<<dim3(8, 32), 256, 0, stream>>>(
        o_bf, w1 + L * 262144, f1_b + L * 512, x_f32, nullptr, t_f32, parts, 512);
    norm_kernel<<<2048, 256, 0, stream>>>(t_f32, parts, n1s, n1b, L, h_f32, h_bf, nullptr);
    gemm_kernel<2, 64><<<dim3(8, 32), 256, 0, stream>>>(
        h_bf, w2 + L * 262144, f2_b + L * 512, h_f32, nullptr, t_f32, parts, 512);
    norm_kernel<<<2048, 256, 0, stream>>>(t_f32, parts, n2s, n2b, L, x_f32, x_bf,
                                          (L == 3) ? (float*)d_out : nullptr);
  }
}